// Round 16
// baseline (573.144 us; speedup 1.0000x reference)
//
#include <hip/hip_runtime.h>

typedef __bf16 bf16x8 __attribute__((ext_vector_type(8)));
typedef float f32x4 __attribute__((ext_vector_type(4)));
typedef float f4 __attribute__((ext_vector_type(4)));
typedef unsigned short us8 __attribute__((ext_vector_type(8)));
typedef unsigned short us4 __attribute__((ext_vector_type(4)));

#define T_TOK 8192
#define DDIM 1024
#define NEXP 8
#define IDIM 2048
#define RROWS 17408                 // cap on sum of 128-aligned per-expert counts
#define ROWS_TOT (T_TOK + RROWS)    // 25600 rows: shared [0,8192), routed at 8192+offs[e]

__device__ __forceinline__ unsigned short f2bf(float f) {
    unsigned u = __float_as_uint(f);
    u += 0x7fffu + ((u >> 16) & 1u);   // round-to-nearest-even
    return (unsigned short)(u >> 16);
}

#define GLDS(src, dst) __builtin_amdgcn_global_load_lds( \
    (const __attribute__((address_space(1))) void*)(src), \
    (__attribute__((address_space(3))) void*)(dst), 16, 0, 0)

// Inline exclusive prefix of 128-aligned counts.
__device__ __forceinline__ int offs_of(const int* __restrict__ cnt, int e) {
    int o = 0;
    for (int i = 0; i < e; i++) o += (cnt[i] + 127) & ~127;
    return o;
}

// ---------------- Router (also emits x in bf16 — cvt fused) ----------------
__global__ __launch_bounds__(256) void router_kernel(
    const float* __restrict__ x, const float* __restrict__ gate_w,
    const float* __restrict__ sgw, float* __restrict__ gate_out,
    float* __restrict__ wdense, float* __restrict__ sgout,
    unsigned short* __restrict__ xb)
{
    __shared__ float lgw[DDIM * NEXP];
    __shared__ float lsg[DDIM];
    int tid = threadIdx.x;
    for (int i = tid; i < (DDIM * NEXP) / 4; i += 256)
        ((f4*)lgw)[i] = ((const f4*)gate_w)[i];
    for (int i = tid; i < DDIM / 4; i += 256)
        ((f4*)lsg)[i] = ((const f4*)sgw)[i];
    __syncthreads();

    int wid = tid >> 6, l = tid & 63;
    int t = blockIdx.x * 4 + wid;

    float acc[NEXP];
#pragma unroll
    for (int e = 0; e < NEXP; e++) acc[e] = 0.f;
    float accs = 0.f;
    const float* xr = x + (size_t)t * DDIM;
    unsigned short* xbr = xb + (size_t)t * DDIM;
#pragma unroll
    for (int j = 0; j < 4; j++) {
        int d0 = j * 256 + l * 4;
        f4 xv = *(const f4*)(xr + d0);
        us4 xo;
#pragma unroll
        for (int c = 0; c < 4; c++) {
            float xd = xv[c];
            xo[c] = f2bf(xd);
            int d = d0 + c;
#pragma unroll
            for (int e = 0; e < NEXP; e++) acc[e] += xd * lgw[d * NEXP + e];
            accs += xd * lsg[d];
        }
        *(us4*)(xbr + d0) = xo;
    }
#pragma unroll
    for (int off = 32; off > 0; off >>= 1) {
#pragma unroll
        for (int e = 0; e < NEXP; e++) acc[e] += __shfl_xor(acc[e], off);
        accs += __shfl_xor(accs, off);
    }
    if (l == 0) {
        float m = acc[0];
        for (int e = 1; e < NEXP; e++) m = fmaxf(m, acc[e]);
        float p[NEXP], s = 0.f;
        for (int e = 0; e < NEXP; e++) { p[e] = __expf(acc[e] - m); s += p[e]; }
        float inv = 1.f / s;
        int i1 = 0; float b1 = p[0];
        for (int e = 1; e < NEXP; e++) if (p[e] > b1) { b1 = p[e]; i1 = e; }
        int i2 = -1; float b2 = -1.f;
        for (int e = 0; e < NEXP; e++) if (e != i1 && p[e] > b2) { b2 = p[e]; i2 = e; }
        for (int e = 0; e < NEXP; e++) {
            gate_out[(size_t)t * NEXP + e] = acc[e];
            float w = (e == i1) ? b1 * inv : (e == i2) ? b2 * inv : 0.f;
            wdense[(size_t)t * NEXP + e] = w;
        }
        sgout[t] = 1.f / (1.f + __expf(-accs));
    }
}

// ---------------- Per-expert compaction (pads to 256-alignment) ----------------
__global__ __launch_bounds__(256) void bucket_kernel(
    const float* __restrict__ wdense, int* __restrict__ list,
    float* __restrict__ wl, int* __restrict__ cnt,
    int* __restrict__ te, int* __restrict__ tp)
{
    int e = blockIdx.x;
    int tid = threadIdx.x, wid = tid >> 6, l = tid & 63;
    __shared__ int wsum[4];
    int base = 0;
    int* le = list + (size_t)e * T_TOK;
    float* we = wl + (size_t)e * T_TOK;
    for (int t0 = 0; t0 < T_TOK; t0 += 256) {
        int tok = t0 + tid;
        float w = wdense[(size_t)tok * NEXP + e];
        bool f = w > 0.f;
        unsigned long long m = __ballot(f);
        int lp = __popcll(m & ((1ull << l) - 1ull));
        if (l == 0) wsum[wid] = __popcll(m);
        __syncthreads();
        int woff = 0;
#pragma unroll
        for (int i = 0; i < 4; i++) if (i < wid) woff += wsum[i];
        int btot = wsum[0] + wsum[1] + wsum[2] + wsum[3];
        if (f) {
            int pos = base + woff + lp;
            le[pos] = tok; we[pos] = w;
            int slot = 0;
            for (int e2 = 0; e2 < e; e2++)
                slot += (wdense[(size_t)tok * NEXP + e2] > 0.f) ? 1 : 0;
            te[tok * 2 + slot] = e;
            tp[tok * 2 + slot] = pos;
        }
        base += btot;
        __syncthreads();
    }
    if (tid == 0) cnt[e] = base;
    int align = (base + 255) & ~255;
    for (int i = base + tid; i < align; i += 256) { le[i] = 0; we[i] = 0.f; }
}

// ---- wcvt gate/up: FULL transpose [DDIM,IDIM] fp32 -> pool[j][IDIM][DDIM] bf16 ----
__global__ __launch_bounds__(256) void wcvt_gu_kernel(
    const float* __restrict__ egw, const float* __restrict__ euw,
    const float* __restrict__ sgp, const float* __restrict__ sup,
    unsigned short* __restrict__ pool)
{
    int j = blockIdx.y;                 // 0..17 = e*2+s, e=8 -> shared
    int e = j >> 1, s = j & 1;
    const float* src = (e < 8) ? ((s ? euw : egw) + (size_t)e * DDIM * IDIM)
                               : (s ? sup : sgp);
    unsigned short* dst = pool + (size_t)j * IDIM * DDIM;
    int tpc = IDIM / 64;                // 32
    int tci = blockIdx.x % tpc, tri = blockIdx.x / tpc;
    int r0 = tri * 64;                  // D row base
    int cg0 = tci * 64;                 // I col base

    __shared__ unsigned short lds[64][72];
    int t = threadIdx.x;
    int tr = t >> 4, tcc = (t & 15) * 4;
#pragma unroll
    for (int jj = 0; jj < 4; jj++) {
        int r = tr + jj * 16;
        f4 v = *(const f4*)(src + (size_t)(r0 + r) * IDIM + cg0 + tcc);
#pragma unroll
        for (int k = 0; k < 4; k++) lds[r][tcc + k] = f2bf(v[k]);
    }
    __syncthreads();
    int orow = t >> 2, ss = t & 3;
    us8 v0, v1;
#pragma unroll
    for (int i = 0; i < 8; i++) {
        v0[i] = lds[ss * 16 + i][orow];
        v1[i] = lds[ss * 16 + 8 + i][orow];
    }
    unsigned short* op = dst + (size_t)(cg0 + orow) * DDIM + r0 + ss * 16;
    *(us8*)op = v0; *(us8*)(op + 8) = v1;
}

// ---- wcvt down: full transpose [IDIM,DDIM] fp32 -> pool[j][DDIM][IDIM] bf16 ----
__global__ __launch_bounds__(256) void wcvt_d_kernel(
    const float* __restrict__ edw, const float* __restrict__ sdw,
    unsigned short* __restrict__ pool)
{
    int j = blockIdx.y;
    const float* src = (j < 8) ? edw + (size_t)j * IDIM * DDIM : sdw;
    unsigned short* dst = pool + (size_t)j * DDIM * IDIM;
    int tpc = DDIM / 64;
    int tci = blockIdx.x % tpc, tri = blockIdx.x / tpc;
    int rg0 = tri * 64;
    int cg0 = tci * 64;

    __shared__ unsigned short lds[64][72];
    int t = threadIdx.x;
    int tr = t >> 4, tcc = (t & 15) * 4;
#pragma unroll
    for (int jj = 0; jj < 4; jj++) {
        int r = tr + jj * 16;
        f4 v = *(const f4*)(src + (size_t)(rg0 + r) * DDIM + cg0 + tcc);
#pragma unroll
        for (int k = 0; k < 4; k++) lds[r][tcc + k] = f2bf(v[k]);
    }
    __syncthreads();
    int orow = t >> 2, ss = t & 3;
    us8 v0, v1;
#pragma unroll
    for (int i = 0; i < 8; i++) {
        v0[i] = lds[ss * 16 + i][orow];
        v1[i] = lds[ss * 16 + 8 + i][orow];
    }
    unsigned short* op = dst + (size_t)(cg0 + orow) * IDIM + rg0 + ss * 16;
    *(us8*)op = v0; *(us8*)(op + 8) = v1;
}

// ---------------- m97 staging helper: 128x32 bf16 tile via global_load_lds ----------------
__device__ __forceinline__ void stage_tile(
    const unsigned short* __restrict__ g, int row0, int ldk, int k0,
    unsigned short* lds, int wid, int lane)
{
#pragma unroll
    for (int j = 0; j < 2; j++) {
        int c = wid + j * 4;              // chunk 0..7, 1KB each
        int seg = c * 64 + lane;          // seg = row*4 + kseg
        int row = seg >> 2, ks = seg & 3;
        const unsigned short* gp = g + (size_t)(row0 + row) * ldk + k0 + ks * 8;
        GLDS(gp, lds + c * 512);
    }
}

// =====================================================================
// r1/m97-faithful gate+up GEMM + SwiGLU.  128x128 tile, BK=32, 4 waves,
// single-buffered LDS, 2-barrier loop, NO manual scheduling.
// routed=0: grid (16, 64), dense shared expert (this exact kernel measured
// 88 us / 780 TF in rounds 1-2).  routed=1: grid (16, 64, 8), A-row gather.
// =====================================================================
__global__ __launch_bounds__(256, 2) void gemm_gu128(
    const unsigned short* __restrict__ A, const unsigned short* __restrict__ pool,
    unsigned short* __restrict__ H, const int* __restrict__ listb,
    const int* __restrict__ cnt, int routed)
{
    const unsigned short *Bg, *Bu; const int* lst; int count, rowb;
    if (!routed) {
        Bg = pool + (size_t)16 * IDIM * DDIM; Bu = pool + (size_t)17 * IDIM * DDIM;
        lst = nullptr; count = T_TOK; rowb = 0;
    } else {
        int e = blockIdx.z;
        Bg = pool + (size_t)(e * 2) * IDIM * DDIM; Bu = pool + (size_t)(e * 2 + 1) * IDIM * DDIM;
        lst = listb + (size_t)e * T_TOK; count = cnt[e]; rowb = T_TOK + offs_of(cnt, e);
    }
    int m0 = blockIdx.y * 128, n0 = blockIdx.x * 128;
    if (m0 >= count) return;
    int climit = (count + 127) & ~127;
    const int K = DDIM;

    __shared__ unsigned short As[128 * 32], Bgs[128 * 32], Bus[128 * 32];
    int tid = threadIdx.x, wid = tid >> 6, l = tid & 63;
    int wm = wid >> 1, wn = wid & 1;
    int lr = l & 15, kg = l >> 4;

    // A-row gather pointers (per-lane global source; LDS dest stays linear).
    int seg0 = wid * 64 + l, seg1 = (wid + 4) * 64 + l;
    int ra0 = seg0 >> 2, ka0 = seg0 & 3;
    int ra1 = seg1 >> 2, ka1 = seg1 & 3;
    int ga0 = lst ? lst[m0 + ra0] : (m0 + ra0);
    int ga1 = lst ? lst[m0 + ra1] : (m0 + ra1);
    const unsigned short* pa0 = A + (size_t)ga0 * K + ka0 * 8;
    const unsigned short* pa1 = A + (size_t)ga1 * K + ka1 * 8;

    f32x4 zero = {0.f, 0.f, 0.f, 0.f};
    f32x4 accg[4][4], accu[4][4];
#pragma unroll
    for (int m = 0; m < 4; m++)
#pragma unroll
        for (int n = 0; n < 4; n++) { accg[m][n] = zero; accu[m][n] = zero; }

    for (int k0 = 0; k0 < K; k0 += 32) {
        GLDS(pa0 + k0, As + wid * 512);
        GLDS(pa1 + k0, As + (wid + 4) * 512);
        stage_tile(Bg, n0, K, k0, Bgs, wid, l);
        stage_tile(Bu, n0, K, k0, Bus, wid, l);
        __syncthreads();
        bf16x8 a[4], bg[4], bu[4];
#pragma unroll
        for (int m = 0; m < 4; m++)
            a[m] = *(const bf16x8*)(As + ((wm * 64 + m * 16 + lr) * 32 + kg * 8));
#pragma unroll
        for (int n = 0; n < 4; n++) {
            bg[n] = *(const bf16x8*)(Bgs + ((wn * 64 + n * 16 + lr) * 32 + kg * 8));
            bu[n] = *(const bf16x8*)(Bus + ((wn * 64 + n * 16 + lr) * 32 + kg * 8));
        }
#pragma unroll
        for (int m = 0; m < 4; m++)
#pragma unroll
            for (int n = 0; n < 4; n++) {
                accg[m][n] = __builtin_amdgcn_mfma_f32_16x16x32_bf16(a[m], bg[n], accg[m][n], 0, 0, 0);
                accu[m][n] = __builtin_amdgcn_mfma_f32_16x16x32_bf16(a[m], bu[n], accu[m][n], 0, 0, 0);
            }
        __syncthreads();
    }

#pragma unroll
    for (int m = 0; m < 4; m++) {
        int rbase = m0 + wm * 64 + m * 16 + kg * 4;
#pragma unroll
        for (int n = 0; n < 4; n++) {
            int col = n0 + wn * 64 + n * 16 + lr;
#pragma unroll
            for (int r = 0; r < 4; r++) {
                int rloc = rbase + r;
                if (rloc < climit) {
                    float g = accg[m][n][r], u = accu[m][n][r];
                    float hv = g * (1.f / (1.f + __expf(-g))) * u;
                    H[(size_t)(rowb + rloc) * IDIM + col] = f2bf(hv);
                }
            }
        }
    }
}

// =====================================================================
// r1/m97-faithful down GEMM.  128x128, BK=32, K=IDIM, single-buffered,
// 2-barrier loop.  Grid (8, 64, 9): z=0 shared, z=1..8 routed.
// coef folded in epilogue, bf16 Y.
// =====================================================================
__global__ __launch_bounds__(256, 2) void gemm_dn128(
    const unsigned short* __restrict__ H, const unsigned short* __restrict__ wd,
    unsigned short* __restrict__ Y,
    const float* __restrict__ wlb, const float* __restrict__ sgo,
    const int* __restrict__ cnt)
{
    int z = blockIdx.z;
    const unsigned short* B; const float* coef; int count, rowb;
    if (z == 0) {
        B = wd + (size_t)8 * DDIM * IDIM;
        coef = sgo; count = T_TOK; rowb = 0;
    } else {
        int e = z - 1;
        B = wd + (size_t)e * DDIM * IDIM;
        coef = wlb + (size_t)e * T_TOK;
        count = cnt[e]; rowb = T_TOK + offs_of(cnt, e);
    }
    int m0 = blockIdx.y * 128, n0 = blockIdx.x * 128;
    if (m0 >= count) return;
    int climit = (count + 127) & ~127;
    const unsigned short* Arows = H + (size_t)rowb * IDIM;

    __shared__ unsigned short As[128 * 32], Bs[128 * 32];
    int tid = threadIdx.x, wid = tid >> 6, l = tid & 63;
    int wm = wid >> 1, wn = wid & 1;
    int lr = l & 15, kg = l >> 4;

    f32x4 zero = {0.f, 0.f, 0.f, 0.f};
    f32x4 acc[4][4];
#pragma unroll
    for (int m = 0; m < 4; m++)
#pragma unroll
        for (int n = 0; n < 4; n++) acc[m][n] = zero;

    for (int k0 = 0; k0 < IDIM; k0 += 32) {
        stage_tile(Arows, m0, IDIM, k0, As, wid, l);
        stage_tile(B, n0, IDIM, k0, Bs, wid, l);
        __syncthreads();
        bf16x8 a[4], b[4];
#pragma unroll
        for (int m = 0; m < 4; m++)
            a[m] = *(const bf16x8*)(As + ((wm * 64 + m * 16 + lr) * 32 + kg * 8));
#pragma unroll
        for (int n = 0; n < 4; n++)
            b[n] = *(const bf16x8*)(Bs + ((wn * 64 + n * 16 + lr) * 32 + kg * 8));
#pragma unroll
        for (int m = 0; m < 4; m++)
#pragma unroll
            for (int n = 0; n < 4; n++)
                acc[m][n] = __builtin_amdgcn_mfma_f32_16x16x32_bf16(a[m], b[n], acc[m][n], 0, 0, 0);
        __syncthreads();
    }

#pragma unroll
    for (int m = 0; m < 4; m++) {
        int rbase = m0 + wm * 64 + m * 16 + kg * 4;
        float cf[4];
#pragma unroll
        for (int r = 0; r < 4; r++) {
            int rloc = rbase + r;
            cf[r] = (rloc < climit) ? coef[rloc] : 0.f;
        }
#pragma unroll
        for (int n = 0; n < 4; n++) {
            int col = n0 + wn * 64 + n * 16 + lr;
#pragma unroll
            for (int r = 0; r < 4; r++) {
                int rloc = rbase + r;
                if (rloc < climit)
                    Y[(size_t)(rowb + rloc) * DDIM + col] = f2bf(cf[r] * acc[m][n][r]);
            }
        }
    }
}

// ---------------- Combine: out[t] = Y[t] + Y[r0] + Y[r1] ----------------
__global__ __launch_bounds__(256) void combine_kernel(
    const unsigned short* __restrict__ Y, const int* __restrict__ te,
    const int* __restrict__ tp, const int* __restrict__ cnt,
    float* __restrict__ out)
{
    int off[NEXP];
    {
        int o = 0;
#pragma unroll
        for (int i = 0; i < NEXP; i++) { off[i] = o; o += (cnt[i] + 127) & ~127; }
    }
    int t = blockIdx.x * 2 + (threadIdx.x >> 7);
    int c = (threadIdx.x & 127) * 8;
    int e0 = te[2 * t], e1 = te[2 * t + 1];
    size_t r0 = (size_t)T_TOK + off[e0] + tp[2 * t];
    size_t r1 = (size_t)T_TOK + off[e1] + tp[2 * t + 1];

    us8 vs = *(const us8*)(Y + (size_t)t * DDIM + c);
    us8 v0 = *(const us8*)(Y + r0 * DDIM + c);
    us8 v1 = *(const us8*)(Y + r1 * DDIM + c);
    f4 o0, o1;
#pragma unroll
    for (int k = 0; k < 4; k++) {
        o0[k] = __uint_as_float((unsigned)vs[k] << 16)
              + __uint_as_float((unsigned)v0[k] << 16)
              + __uint_as_float((unsigned)v1[k] << 16);
        o1[k] = __uint_as_float((unsigned)vs[4 + k] << 16)
              + __uint_as_float((unsigned)v0[4 + k] << 16)
              + __uint_as_float((unsigned)v1[4 + k] << 16);
    }
    float* op = out + (size_t)t * DDIM + c;
    *(f4*)op = o0;
    *(f4*)(op + 4) = o1;
}

extern "C" void kernel_launch(void* const* d_in, const int* in_sizes, int n_in,
                              void* d_out, int out_size, void* d_ws, size_t ws_size,
                              hipStream_t stream)
{
    const float* x   = (const float*)d_in[0];
    const float* gw  = (const float*)d_in[1];
    const float* egw = (const float*)d_in[2];
    const float* euw = (const float*)d_in[3];
    const float* edw = (const float*)d_in[4];
    const float* sgp = (const float*)d_in[5];
    const float* sup = (const float*)d_in[6];
    const float* sdw = (const float*)d_in[7];
    const float* seg = (const float*)d_in[8];

    float* out0 = (float*)d_out;
    float* gate_out = out0 + (size_t)T_TOK * DDIM;

    // Workspace (~236 MB; r2's passing config demonstrated >=294 MB available).
    // Y aliases guPool: gate/up weights are dead once gemm_gu finishes, and
    // gemm_dn (the only Y writer) runs strictly after (stream-serial).
    char* ws = (char*)d_ws;
    auto take = [&](size_t bytes) { char* p = ws; ws += (bytes + 255) & ~(size_t)255; return p; };
    unsigned short* xb   = (unsigned short*)take((size_t)T_TOK * DDIM * 2);
    float* wdense = (float*)take((size_t)T_TOK * NEXP * 4);
    float* sgo    = (float*)take((size_t)T_TOK * 4);
    int*   list   = (int*)take((size_t)NEXP * T_TOK * 4);
    float* wl     = (float*)take((size_t)NEXP * T_TOK * 4);
    int*   cnt    = (int*)take(256);
    int*   te     = (int*)take((size_t)T_TOK * 2 * 4);
    int*   tp     = (int*)take((size_t)T_TOK * 2 * 4);
    unsigned short* guPool = (unsigned short*)take((size_t)18 * IDIM * DDIM * 2);  // 75.5 MB
    unsigned short* wdPool = (unsigned short*)take((size_t)9 * DDIM * IDIM * 2);   // 37.75 MB
    unsigned short* H      = (unsigned short*)take((size_t)ROWS_TOT * IDIM * 2);   // 104.9 MB
    unsigned short* Y      = guPool;   // alias (52.4 MB needed <= 75.5 MB available)

    router_kernel<<<T_TOK / 4, 256, 0, stream>>>(x, gw, seg, gate_out, wdense, sgo, xb);
    bucket_kernel<<<NEXP, 256, 0, stream>>>(wdense, list, wl, cnt, te, tp);

    // Full-width weight transposes (single launches).
    wcvt_gu_kernel<<<dim3((IDIM / 64) * (DDIM / 64), 18), 256, 0, stream>>>(
        egw, euw, sgp, sup, guPool);

    // Gate+up: dense shared expert (r2's measured-88us kernel), then routed batch.
    gemm_gu128<<<dim3(IDIM / 128, T_TOK / 128), 256, 0, stream>>>(
        xb, guPool, H, list, cnt, 0);
    gemm_gu128<<<dim3(IDIM / 128, T_TOK / 128, NEXP), 256, 0, stream>>>(
        xb, guPool, H, list, cnt, 1);

    // Down weights, then down GEMM (z-batched), writing Y over the dead gu pool.
    wcvt_d_kernel<<<dim3((DDIM / 64) * (IDIM / 64), 9), 256, 0, stream>>>(
        edw, sdw, wdPool);
    gemm_dn128<<<dim3(DDIM / 128, T_TOK / 128, 9), 256, 0, stream>>>(
        H, wdPool, Y, wl, sgo, cnt);

    combine_kernel<<<T_TOK / 2, 256, 0, stream>>>(Y, te, tp, cnt, out0);
}

// Round 17
// 544.815 us; speedup vs baseline: 1.0520x; 1.0520x over previous
//
#include <hip/hip_runtime.h>

typedef __bf16 bf16x8 __attribute__((ext_vector_type(8)));
typedef float f32x4 __attribute__((ext_vector_type(4)));
typedef float f4 __attribute__((ext_vector_type(4)));
typedef unsigned short us8 __attribute__((ext_vector_type(8)));
typedef unsigned short us4 __attribute__((ext_vector_type(4)));

#define T_TOK 8192
#define DDIM 1024
#define NEXP 8
#define IDIM 2048
#define NCH 1024                    // gateup N-chunk (weight pool half)
#define RROWS 17408                 // cap on sum of 128-aligned per-expert counts
#define ROWS_TOT (T_TOK + RROWS)    // 25600 rows: shared [0,8192), routed at 8192+offs[e]

__device__ __forceinline__ unsigned short f2bf(float f) {
    unsigned u = __float_as_uint(f);
    u += 0x7fffu + ((u >> 16) & 1u);   // round-to-nearest-even
    return (unsigned short)(u >> 16);
}

#define GLDS(src, dst) __builtin_amdgcn_global_load_lds( \
    (const __attribute__((address_space(1))) void*)(src), \
    (__attribute__((address_space(3))) void*)(dst), 16, 0, 0)

// ---------------- Router (also emits x in bf16 — cvt fused) ----------------
__global__ __launch_bounds__(256) void router_kernel(
    const float* __restrict__ x, const float* __restrict__ gate_w,
    const float* __restrict__ sgw, float* __restrict__ gate_out,
    float* __restrict__ wdense, float* __restrict__ sgout,
    unsigned short* __restrict__ xb)
{
    __shared__ float lgw[DDIM * NEXP];
    __shared__ float lsg[DDIM];
    int tid = threadIdx.x;
    for (int i = tid; i < (DDIM * NEXP) / 4; i += 256)
        ((f4*)lgw)[i] = ((const f4*)gate_w)[i];
    for (int i = tid; i < DDIM / 4; i += 256)
        ((f4*)lsg)[i] = ((const f4*)sgw)[i];
    __syncthreads();

    int wid = tid >> 6, l = tid & 63;
    int t = blockIdx.x * 4 + wid;

    float acc[NEXP];
#pragma unroll
    for (int e = 0; e < NEXP; e++) acc[e] = 0.f;
    float accs = 0.f;
    const float* xr = x + (size_t)t * DDIM;
    unsigned short* xbr = xb + (size_t)t * DDIM;
#pragma unroll
    for (int j = 0; j < 4; j++) {
        int d0 = j * 256 + l * 4;
        f4 xv = *(const f4*)(xr + d0);
        us4 xo;
#pragma unroll
        for (int c = 0; c < 4; c++) {
            float xd = xv[c];
            xo[c] = f2bf(xd);
            int d = d0 + c;
#pragma unroll
            for (int e = 0; e < NEXP; e++) acc[e] += xd * lgw[d * NEXP + e];
            accs += xd * lsg[d];
        }
        *(us4*)(xbr + d0) = xo;
    }
#pragma unroll
    for (int off = 32; off > 0; off >>= 1) {
#pragma unroll
        for (int e = 0; e < NEXP; e++) acc[e] += __shfl_xor(acc[e], off);
        accs += __shfl_xor(accs, off);
    }
    if (l == 0) {
        float m = acc[0];
        for (int e = 1; e < NEXP; e++) m = fmaxf(m, acc[e]);
        float p[NEXP], s = 0.f;
        for (int e = 0; e < NEXP; e++) { p[e] = __expf(acc[e] - m); s += p[e]; }
        float inv = 1.f / s;
        int i1 = 0; float b1 = p[0];
        for (int e = 1; e < NEXP; e++) if (p[e] > b1) { b1 = p[e]; i1 = e; }
        int i2 = -1; float b2 = -1.f;
        for (int e = 0; e < NEXP; e++) if (e != i1 && p[e] > b2) { b2 = p[e]; i2 = e; }
        for (int e = 0; e < NEXP; e++) {
            gate_out[(size_t)t * NEXP + e] = acc[e];
            float w = (e == i1) ? b1 * inv : (e == i2) ? b2 * inv : 0.f;
            wdense[(size_t)t * NEXP + e] = w;
        }
        sgout[t] = 1.f / (1.f + __expf(-accs));
    }
}

// ---------------- Per-expert compaction (pads to 256-alignment) ----------------
__global__ __launch_bounds__(256) void bucket_kernel(
    const float* __restrict__ wdense, int* __restrict__ list,
    float* __restrict__ wl, int* __restrict__ cnt,
    int* __restrict__ te, int* __restrict__ tp)
{
    int e = blockIdx.x;
    int tid = threadIdx.x, wid = tid >> 6, l = tid & 63;
    __shared__ int wsum[4];
    int base = 0;
    int* le = list + (size_t)e * T_TOK;
    float* we = wl + (size_t)e * T_TOK;
    for (int t0 = 0; t0 < T_TOK; t0 += 256) {
        int tok = t0 + tid;
        float w = wdense[(size_t)tok * NEXP + e];
        bool f = w > 0.f;
        unsigned long long m = __ballot(f);
        int lp = __popcll(m & ((1ull << l) - 1ull));
        if (l == 0) wsum[wid] = __popcll(m);
        __syncthreads();
        int woff = 0;
#pragma unroll
        for (int i = 0; i < 4; i++) if (i < wid) woff += wsum[i];
        int btot = wsum[0] + wsum[1] + wsum[2] + wsum[3];
        if (f) {
            int pos = base + woff + lp;
            le[pos] = tok; we[pos] = w;
            int slot = 0;
            for (int e2 = 0; e2 < e; e2++)
                slot += (wdense[(size_t)tok * NEXP + e2] > 0.f) ? 1 : 0;
            te[tok * 2 + slot] = e;
            tp[tok * 2 + slot] = pos;
        }
        base += btot;
        __syncthreads();
    }
    if (tid == 0) cnt[e] = base;
    int align = (base + 255) & ~255;
    for (int i = base + tid; i < align; i += 256) { le[i] = 0; we[i] = 0.f; }
}

// ---------------- Exclusive scan of 128-aligned counts ----------------
__global__ void scan_kernel(const int* __restrict__ cnt, int* __restrict__ offs)
{
    if (threadIdx.x == 0) {
        int o = 0;
        for (int e = 0; e < NEXP; e++) { offs[e] = o; o += (cnt[e] + 127) & ~127; }
    }
}

// ---- wcvt gate/up: transpose chunk cols of [DDIM,IDIM] fp32 -> pool[j][NCH][DDIM] bf16 ----
__global__ __launch_bounds__(256) void wcvt_gu_kernel(
    const float* __restrict__ egw, const float* __restrict__ euw,
    const float* __restrict__ sgp, const float* __restrict__ sup,
    unsigned short* __restrict__ pool, int c0)
{
    int j = blockIdx.y;
    int e = j >> 1, s = j & 1;
    const float* src = (e < 8) ? ((s ? euw : egw) + (size_t)e * DDIM * IDIM)
                               : (s ? sup : sgp);
    unsigned short* dst = pool + (size_t)j * NCH * DDIM;
    int tpc = NCH / 64;
    int tci = blockIdx.x % tpc, tri = blockIdx.x / tpc;
    int r0 = tri * 64;
    int cl0 = tci * 64;
    int cg0 = c0 + cl0;

    __shared__ unsigned short lds[64][72];
    int t = threadIdx.x;
    int tr = t >> 4, tcc = (t & 15) * 4;
#pragma unroll
    for (int jj = 0; jj < 4; jj++) {
        int r = tr + jj * 16;
        f4 v = *(const f4*)(src + (size_t)(r0 + r) * IDIM + cg0 + tcc);
#pragma unroll
        for (int k = 0; k < 4; k++) lds[r][tcc + k] = f2bf(v[k]);
    }
    __syncthreads();
    int orow = t >> 2, ss = t & 3;
    us8 v0, v1;
#pragma unroll
    for (int i = 0; i < 8; i++) {
        v0[i] = lds[ss * 16 + i][orow];
        v1[i] = lds[ss * 16 + 8 + i][orow];
    }
    unsigned short* op = dst + (size_t)(cl0 + orow) * DDIM + r0 + ss * 16;
    *(us8*)op = v0; *(us8*)(op + 8) = v1;
}

// ---- wcvt down: full transpose [IDIM,DDIM] fp32 -> pool[j][DDIM][IDIM] bf16 ----
__global__ __launch_bounds__(256) void wcvt_d_kernel(
    const float* __restrict__ edw, const float* __restrict__ sdw,
    unsigned short* __restrict__ pool)
{
    int j = blockIdx.y;
    const float* src = (j < 8) ? edw + (size_t)j * IDIM * DDIM : sdw;
    unsigned short* dst = pool + (size_t)j * DDIM * IDIM;
    int tpc = DDIM / 64;
    int tci = blockIdx.x % tpc, tri = blockIdx.x / tpc;
    int rg0 = tri * 64;
    int cg0 = tci * 64;

    __shared__ unsigned short lds[64][72];
    int t = threadIdx.x;
    int tr = t >> 4, tcc = (t & 15) * 4;
#pragma unroll
    for (int jj = 0; jj < 4; jj++) {
        int r = tr + jj * 16;
        f4 v = *(const f4*)(src + (size_t)(rg0 + r) * DDIM + cg0 + tcc);
#pragma unroll
        for (int k = 0; k < 4; k++) lds[r][tcc + k] = f2bf(v[k]);
    }
    __syncthreads();
    int orow = t >> 2, ss = t & 3;
    us8 v0, v1;
#pragma unroll
    for (int i = 0; i < 8; i++) {
        v0[i] = lds[ss * 16 + i][orow];
        v1[i] = lds[ss * 16 + 8 + i][orow];
    }
    unsigned short* op = dst + (size_t)(cg0 + orow) * IDIM + rg0 + ss * 16;
    *(us8*)op = v0; *(us8*)(op + 8) = v1;
}

// =====================================================================
// 8-phase 256-tile gate+up GEMM + SwiGLU.  BM=256, BN=128, BK=64.
// 8 waves (4M x 2N), per-wave 64x64 dual (g,u).
// launch_bounds (512,1): 128 KiB LDS caps at 1 block/CU regardless.
// =====================================================================
__global__ __launch_bounds__(512, 1) void gemm_gateup8(
    const unsigned short* __restrict__ A, const unsigned short* __restrict__ pool,
    unsigned short* __restrict__ H, const int* __restrict__ listb,
    const int* __restrict__ cnt, const int* __restrict__ offs, int c0)
{
    int z = blockIdx.z;
    const unsigned short *Bg, *Bu; const int* lst; int count, rowb;
    if (z == 0) {
        Bg = pool + (size_t)16 * NCH * DDIM; Bu = pool + (size_t)17 * NCH * DDIM;
        lst = nullptr; count = T_TOK; rowb = 0;
    } else {
        int e = z - 1;
        Bg = pool + (size_t)(e * 2) * NCH * DDIM; Bu = pool + (size_t)(e * 2 + 1) * NCH * DDIM;
        lst = listb + (size_t)e * T_TOK; count = cnt[e]; rowb = T_TOK + offs[e];
    }
    int m0 = blockIdx.y * 256, n0 = blockIdx.x * 128;
    if (m0 >= count) return;
    int climit = (count + 127) & ~127;
    const int NT = DDIM / 64;   // 16

    __shared__ unsigned short lds[2][32768];   // 128 KiB

    int tid = threadIdx.x, wid = tid >> 6, l = tid & 63;
    int wm = wid >> 1, wn = wid & 1;
    int lr = l & 15, lkg = l >> 4;

    int sb = tid & 7, sr = tid >> 3;
    int sk = (sb ^ (sr & 7)) << 3;
    const unsigned short* pa[2][2];
#pragma unroll
    for (int h = 0; h < 2; h++)
#pragma unroll
        for (int j = 0; j < 2; j++) {
            int rr = m0 + h * 128 + j * 64 + sr;
            int ga = lst ? lst[rr] : rr;
            pa[h][j] = A + (size_t)ga * DDIM + sk;
        }
    const unsigned short* pbg = Bg + (size_t)(n0 + sr) * DDIM + sk;
    const unsigned short* pbu = Bu + (size_t)(n0 + sr) * DDIM + sk;

#define GU_ST_A(sbuf, h, t) { \
    GLDS(pa[h][0] + (t) * 64, (sbuf) + (h) * 8192 + tid * 8); \
    GLDS(pa[h][1] + (t) * 64, (sbuf) + (h) * 8192 + 4096 + tid * 8); }
#define GU_ST_BG(sbuf, t) { \
    GLDS(pbg + (t) * 64, (sbuf) + 16384 + tid * 8); \
    GLDS(pbg + (size_t)64 * DDIM + (t) * 64, (sbuf) + 16384 + 4096 + tid * 8); }
#define GU_ST_BU(sbuf, t) { \
    GLDS(pbu + (t) * 64, (sbuf) + 24576 + tid * 8); \
    GLDS(pbu + (size_t)64 * DDIM + (t) * 64, (sbuf) + 24576 + 4096 + tid * 8); }

    {
        unsigned short* s0 = &lds[0][0];
        GU_ST_A(s0, 0, 0); GU_ST_A(s0, 1, 0); GU_ST_BG(s0, 0); GU_ST_BU(s0, 0);
        unsigned short* s1 = &lds[1][0];
        GU_ST_A(s1, 0, 1); GU_ST_A(s1, 1, 1); GU_ST_BG(s1, 1); GU_ST_BU(s1, 1);
    }

    int xorc = (lr & 7) << 3;
    int kx0 = (lkg * 8) ^ xorc;
    int kx1 = (32 + lkg * 8) ^ xorc;
    int aoff[4], boff[4];
#pragma unroll
    for (int mf = 0; mf < 4; mf++) {
        int r = wm * 64 + mf * 16 + lr;
        aoff[mf] = (r >> 7) * 8192 + (r & 127) * 64;
    }
#pragma unroll
    for (int nf = 0; nf < 4; nf++)
        boff[nf] = 16384 + (wn * 64 + nf * 16 + lr) * 64;

    f32x4 zero = {0.f, 0.f, 0.f, 0.f};
    f32x4 accg[4][4], accu[4][4];
#pragma unroll
    for (int m = 0; m < 4; m++)
#pragma unroll
        for (int n = 0; n < 4; n++) { accg[m][n] = zero; accu[m][n] = zero; }

    bf16x8 a[2][2], bg[4][2], bu[4][2];

#pragma unroll 1
    for (int t = 0; t < NT; t++) {
        const unsigned short* cb = &lds[t & 1][0];
        unsigned short* sbuf = &lds[t & 1][0];
        bool stg = (t + 2 < NT);

        // ---- P1: quadrant (mh0, nh0) ----
        if (t == NT - 1) { asm volatile("s_waitcnt vmcnt(0)" ::: "memory"); }
        else             { asm volatile("s_waitcnt vmcnt(8)" ::: "memory"); }
        __builtin_amdgcn_s_barrier();
#pragma unroll
        for (int mf = 0; mf < 2; mf++) {
            a[mf][0] = *(const bf16x8*)(cb + aoff[mf] + kx0);
            a[mf][1] = *(const bf16x8*)(cb + aoff[mf] + kx1);
        }
#pragma unroll
        for (int nf = 0; nf < 2; nf++) {
            bg[nf][0] = *(const bf16x8*)(cb + boff[nf] + kx0);
            bg[nf][1] = *(const bf16x8*)(cb + boff[nf] + kx1);
            bu[nf][0] = *(const bf16x8*)(cb + boff[nf] + 8192 + kx0);
            bu[nf][1] = *(const bf16x8*)(cb + boff[nf] + 8192 + kx1);
        }
        __builtin_amdgcn_s_setprio(1);
#pragma unroll
        for (int kh = 0; kh < 2; kh++)
#pragma unroll
            for (int mf = 0; mf < 2; mf++)
#pragma unroll
                for (int nf = 0; nf < 2; nf++) {
                    accg[mf][nf] = __builtin_amdgcn_mfma_f32_16x16x32_bf16(a[mf][kh], bg[nf][kh], accg[mf][nf], 0, 0, 0);
                    accu[mf][nf] = __builtin_amdgcn_mfma_f32_16x16x32_bf16(a[mf][kh], bu[nf][kh], accu[mf][nf], 0, 0, 0);
                }
        __builtin_amdgcn_s_setprio(0);

        // ---- P2: (mh0, nh1) ----
        __builtin_amdgcn_s_barrier();
#pragma unroll
        for (int nf = 2; nf < 4; nf++) {
            bg[nf][0] = *(const bf16x8*)(cb + boff[nf] + kx0);
            bg[nf][1] = *(const bf16x8*)(cb + boff[nf] + kx1);
            bu[nf][0] = *(const bf16x8*)(cb + boff[nf] + 8192 + kx0);
            bu[nf][1] = *(const bf16x8*)(cb + boff[nf] + 8192 + kx1);
        }
        __builtin_amdgcn_s_setprio(1);
#pragma unroll
        for (int kh = 0; kh < 2; kh++)
#pragma unroll
            for (int mf = 0; mf < 2; mf++)
#pragma unroll
                for (int nf = 2; nf < 4; nf++) {
                    accg[mf][nf] = __builtin_amdgcn_mfma_f32_16x16x32_bf16(a[mf][kh], bg[nf][kh], accg[mf][nf], 0, 0, 0);
                    accu[mf][nf] = __builtin_amdgcn_mfma_f32_16x16x32_bf16(a[mf][kh], bu[nf][kh], accu[mf][nf], 0, 0, 0);
                }
        __builtin_amdgcn_s_setprio(0);

        // ---- P3: (mh1, nh0); stage Bg(t+2) ----
        __builtin_amdgcn_s_barrier();
#pragma unroll
        for (int mf = 0; mf < 2; mf++) {
            a[mf][0] = *(const bf16x8*)(cb + aoff[2 + mf] + kx0);
            a[mf][1] = *(const bf16x8*)(cb + aoff[2 + mf] + kx1);
        }
        if (stg) { GU_ST_BG(sbuf, t + 2); }
        __builtin_amdgcn_s_setprio(1);
#pragma unroll
        for (int kh = 0; kh < 2; kh++)
#pragma unroll
            for (int mf = 0; mf < 2; mf++)
#pragma unroll
                for (int nf = 0; nf < 2; nf++) {
                    accg[2 + mf][nf] = __builtin_amdgcn_mfma_f32_16x16x32_bf16(a[mf][kh], bg[nf][kh], accg[2 + mf][nf], 0, 0, 0);
                    accu[2 + mf][nf] = __builtin_amdgcn_mfma_f32_16x16x32_bf16(a[mf][kh], bu[nf][kh], accu[2 + mf][nf], 0, 0, 0);
                }
        __builtin_amdgcn_s_setprio(0);

        // ---- P4: (mh1, nh1); stage Bu, A0, A1 (t+2) ----
        __builtin_amdgcn_s_barrier();
        if (stg) { GU_ST_BU(sbuf, t + 2); GU_ST_A(sbuf, 0, t + 2); GU_ST_A(sbuf, 1, t + 2); }
        __builtin_amdgcn_s_setprio(1);
#pragma unroll
        for (int kh = 0; kh < 2; kh++)
#pragma unroll
            for (int mf = 0; mf < 2; mf++)
#pragma unroll
                for (int nf = 2; nf < 4; nf++) {
                    accg[2 + mf][nf] = __builtin_amdgcn_mfma_f32_16x16x32_bf16(a[mf][kh], bg[nf][kh], accg[2 + mf][nf], 0, 0, 0);
                    accu[2 + mf][nf] = __builtin_amdgcn_mfma_f32_16x16x32_bf16(a[mf][kh], bu[nf][kh], accu[2 + mf][nf], 0, 0, 0);
                }
        __builtin_amdgcn_s_setprio(0);
    }

    // ---- epilogue: SwiGLU, guarded writes ----
#pragma unroll
    for (int mf = 0; mf < 4; mf++) {
        int rbase = m0 + wm * 64 + mf * 16 + lkg * 4;
#pragma unroll
        for (int nf = 0; nf < 4; nf++) {
            int col = c0 + n0 + wn * 64 + nf * 16 + lr;
#pragma unroll
            for (int r = 0; r < 4; r++) {
                int rloc = rbase + r;
                if (rloc < climit) {
                    float g = accg[mf][nf][r], u = accu[mf][nf][r];
                    float hv = g * (1.f / (1.f + __expf(-g))) * u;
                    H[(size_t)(rowb + rloc) * IDIM + col] = f2bf(hv);
                }
            }
        }
    }
}

// =====================================================================
// 8-phase 256x256 down GEMM, K=IDIM, coef in epilogue, bf16 Y.
// 8 waves (2M x 4N), per-wave 128x64.  LDS: A[256][64]@0, B[256][64]@16384.
// =====================================================================
__global__ __launch_bounds__(512, 2) void gemm_down8(
    const unsigned short* __restrict__ H, const unsigned short* __restrict__ pool,
    unsigned short* __restrict__ Y,
    const float* __restrict__ wlb, const float* __restrict__ sgo,
    const int* __restrict__ cnt, const int* __restrict__ offs)
{
    int z = blockIdx.z;
    const unsigned short* B; const float* coef; int count, rowb;
    if (z == 0) {
        B = pool + (size_t)8 * DDIM * IDIM;
        coef = sgo; count = T_TOK; rowb = 0;
    } else {
        int e = z - 1;
        B = pool + (size_t)e * DDIM * IDIM;
        coef = wlb + (size_t)e * T_TOK;
        count = cnt[e]; rowb = T_TOK + offs[e];
    }
    int m0 = blockIdx.y * 256, n0 = blockIdx.x * 256;
    if (m0 >= count) return;
    int climit = (count + 127) & ~127;
    const int NT = IDIM / 64;   // 32

    __shared__ unsigned short lds[2][32768];   // 128 KiB

    int tid = threadIdx.x, wid = tid >> 6, l = tid & 63;
    int wm = wid >> 2, wn = wid & 3;
    int lr = l & 15, lkg = l >> 4;

    int sb = tid & 7, sr = tid >> 3;
    int sk = (sb ^ (sr & 7)) << 3;
    const unsigned short* pah = H + (size_t)(rowb + m0 + sr) * IDIM + sk;
    const unsigned short* pb  = B + (size_t)(n0 + sr) * IDIM + sk;

#define DN_ST_A(sbuf, h, t) { \
    GLDS(pah + (size_t)((h) * 128) * IDIM + (t) * 64, (sbuf) + (h) * 8192 + tid * 8); \
    GLDS(pah + (size_t)((h) * 128 + 64) * IDIM + (t) * 64, (sbuf) + (h) * 8192 + 4096 + tid * 8); }
#define DN_ST_B(sbuf, h, t) { \
    GLDS(pb + (size_t)((h) * 128) * IDIM + (t) * 64, (sbuf) + 16384 + (h) * 8192 + tid * 8); \
    GLDS(pb + (size_t)((h) * 128 + 64) * IDIM + (t) * 64, (sbuf) + 16384 + (h) * 8192 + 4096 + tid * 8); }

    {
        unsigned short* s0 = &lds[0][0];
        DN_ST_A(s0, 0, 0); DN_ST_A(s0, 1, 0); DN_ST_B(s0, 0, 0); DN_ST_B(s0, 1, 0);
        unsigned short* s1 = &lds[1][0];
        DN_ST_A(s1, 0, 1); DN_ST_A(s1, 1, 1); DN_ST_B(s1, 0, 1); DN_ST_B(s1, 1, 1);
    }

    int xorc = (lr & 7) << 3;
    int kx0 = (lkg * 8) ^ xorc;
    int kx1 = (32 + lkg * 8) ^ xorc;
    int aoff[8], boff[4];
#pragma unroll
    for (int mf = 0; mf < 8; mf++)
        aoff[mf] = wm * 8192 + (mf * 16 + lr) * 64;
#pragma unroll
    for (int nf = 0; nf < 4; nf++)
        boff[nf] = 16384 + (wn * 64 + nf * 16 + lr) * 64;

    f32x4 zero = {0.f, 0.f, 0.f, 0.f};
    f32x4 acc[8][4];
#pragma unroll
    for (int m = 0; m < 8; m++)
#pragma unroll
        for (int n = 0; n < 4; n++) acc[m][n] = zero;

    bf16x8 a[4][2], b[4][2];

#pragma unroll 1
    for (int t = 0; t < NT; t++) {
        const unsigned short* cb = &lds[t & 1][0];
        unsigned short* sbuf = &lds[t & 1][0];
        bool stg = (t + 2 < NT);

        // ---- P1: mf0-3 x nf0-1 ----
        if (t == NT - 1) { asm volatile("s_waitcnt vmcnt(0)" ::: "memory"); }
        else             { asm volatile("s_waitcnt vmcnt(8)" ::: "memory"); }
        __builtin_amdgcn_s_barrier();
#pragma unroll
        for (int mf = 0; mf < 4; mf++) {
            a[mf][0] = *(const bf16x8*)(cb + aoff[mf] + kx0);
            a[mf][1] = *(const bf16x8*)(cb + aoff[mf] + kx1);
        }
#pragma unroll
        for (int nf = 0; nf < 2; nf++) {
            b[nf][0] = *(const bf16x8*)(cb + boff[nf] + kx0);
            b[nf][1] = *(const bf16x8*)(cb + boff[nf] + kx1);
        }
        __builtin_amdgcn_s_setprio(1);
#pragma unroll
        for (int kh = 0; kh < 2; kh++)
#pragma unroll
            for (int mf = 0; mf < 4; mf++)
#pragma unroll
                for (int nf = 0; nf < 2; nf++)
                    acc[mf][nf] = __builtin_amdgcn_mfma_f32_16x16x32_bf16(a[mf][kh], b[nf][kh], acc[mf][nf], 0, 0, 0);
        __builtin_amdgcn_s_setprio(0);

        // ---- P2: mf0-3 x nf2-3 ----
        __builtin_amdgcn_s_barrier();
#pragma unroll
        for (int nf = 2; nf < 4; nf++) {
            b[nf][0] = *(const bf16x8*)(cb + boff[nf] + kx0);
            b[nf][1] = *(const bf16x8*)(cb + boff[nf] + kx1);
        }
        __builtin_amdgcn_s_setprio(1);
#pragma unroll
        for (int kh = 0; kh < 2; kh++)
#pragma unroll
            for (int mf = 0; mf < 4; mf++)
#pragma unroll
                for (int nf = 2; nf < 4; nf++)
                    acc[mf][nf] = __builtin_amdgcn_mfma_f32_16x16x32_bf16(a[mf][kh], b[nf][kh], acc[mf][nf], 0, 0, 0);
        __builtin_amdgcn_s_setprio(0);

        // ---- P3: mf4-7 x nf0-1; stage B0(t+2) ----
        __builtin_amdgcn_s_barrier();
#pragma unroll
        for (int mf = 0; mf < 4; mf++) {
            a[mf][0] = *(const bf16x8*)(cb + aoff[4 + mf] + kx0);
            a[mf][1] = *(const bf16x8*)(cb + aoff[4 + mf] + kx1);
        }
        if (stg) { DN_ST_B(sbuf, 0, t + 2); }
        __builtin_amdgcn_s_setprio(1);
#pragma unroll
        for (int kh = 0; kh < 2; kh++)
#pragma unroll
            for (int mf = 0; mf < 4; mf++)
#pragma unroll
                for (int nf = 0; nf < 2; nf++)
                    acc[4 + mf][nf] = __builtin_amdgcn_mfma_f32_16x16x32_bf16(a[mf][kh], b[nf][kh], acc[4 + mf][nf], 0, 0, 0);
        __builtin_amdgcn_s_setprio(0);

        // ---- P4: mf4-7 x nf2-3; stage B1, A0, A1 (t+2) ----
        __builtin_amdgcn_s_barrier();
        if (stg) { DN_ST_B(sbuf, 1, t + 2); DN_ST_A(sbuf, 0, t + 2); DN_ST_A(sbuf, 1, t + 2); }
        __builtin_amdgcn_s_setprio(1);
#pragma unroll
        for (int kh = 0; kh < 2; kh++)
#pragma unroll
            for (int mf = 0; mf < 4; mf++)
#pragma unroll
                for (int nf = 2; nf < 4; nf++)
                    acc[4 + mf][nf] = __builtin_amdgcn_mfma_f32_16x16x32_bf16(a[mf][kh], b[nf][kh], acc[4 + mf][nf], 0, 0, 0);
        __builtin_amdgcn_s_setprio(0);
    }

    // ---- epilogue: coef * acc -> bf16 Y, guarded ----
#pragma unroll
    for (int mf = 0; mf < 8; mf++) {
        int rbase = m0 + wm * 128 + mf * 16 + lkg * 4;
        float cf[4];
#pragma unroll
        for (int r = 0; r < 4; r++) {
            int rloc = rbase + r;
            cf[r] = (rloc < climit) ? coef[rloc] : 0.f;
        }
#pragma unroll
        for (int nf = 0; nf < 4; nf++) {
            int col = n0 + wn * 64 + nf * 16 + lr;
#pragma unroll
            for (int r = 0; r < 4; r++) {
                int rloc = rbase + r;
                if (rloc < climit)
                    Y[(size_t)(rowb + rloc) * DDIM + col] = f2bf(cf[r] * acc[mf][nf][r]);
            }
        }
    }
}

// ---------------- Combine: out[t] = Y[t] + Y[r0] + Y[r1] ----------------
__global__ __launch_bounds__(256) void combine_kernel(
    const unsigned short* __restrict__ Y, const int* __restrict__ te,
    const int* __restrict__ tp, const int* __restrict__ offs,
    float* __restrict__ out)
{
    int t = blockIdx.x * 2 + (threadIdx.x >> 7);
    int c = (threadIdx.x & 127) * 8;
    int e0 = te[2 * t], e1 = te[2 * t + 1];
    size_t r0 = (size_t)T_TOK + offs[e0] + tp[2 * t];
    size_t r1 = (size_t)T_TOK + offs[e1] + tp[2 * t + 1];

    us8 vs = *(const us8*)(Y + (size_t)t * DDIM + c);
    us8 v0 = *(const us8*)(Y + r0 * DDIM + c);
    us8 v1 = *(const us8*)(Y + r1 * DDIM + c);
    f4 o0, o1;
#pragma unroll
    for (int k = 0; k < 4; k++) {
        o0[k] = __uint_as_float((unsigned)vs[k] << 16)
              + __uint_as_float((unsigned)v0[k] << 16)
              + __uint_as_float((unsigned)v1[k] << 16);
        o1[k] = __uint_as_float((unsigned)vs[4 + k] << 16)
              + __uint_as_float((unsigned)v0[4 + k] << 16)
              + __uint_as_float((unsigned)v1[4 + k] << 16);
    }
    float* op = out + (size_t)t * DDIM + c;
    *(f4*)op = o0;
    *(f4*)(op + 4) = o1;
}

extern "C" void kernel_launch(void* const* d_in, const int* in_sizes, int n_in,
                              void* d_out, int out_size, void* d_ws, size_t ws_size,
                              hipStream_t stream)
{
    const float* x   = (const float*)d_in[0];
    const float* gw  = (const float*)d_in[1];
    const float* egw = (const float*)d_in[2];
    const float* euw = (const float*)d_in[3];
    const float* edw = (const float*)d_in[4];
    const float* sgp = (const float*)d_in[5];
    const float* sup = (const float*)d_in[6];
    const float* sdw = (const float*)d_in[7];
    const float* seg = (const float*)d_in[8];

    float* out0 = (float*)d_out;
    float* gate_out = out0 + (size_t)T_TOK * DDIM;

    // Workspace layout: byte-identical to the round-5..15 passing footprint.
    char* ws = (char*)d_ws;
    auto take = [&](size_t bytes) { char* p = ws; ws += (bytes + 255) & ~(size_t)255; return p; };
    unsigned short* xb   = (unsigned short*)take((size_t)T_TOK * DDIM * 2);
    float* wdense = (float*)take((size_t)T_TOK * NEXP * 4);
    float* sgo    = (float*)take((size_t)T_TOK * 4);
    int*   list   = (int*)take((size_t)NEXP * T_TOK * 4);
    float* wl     = (float*)take((size_t)NEXP * T_TOK * 4);
    int*   cnt    = (int*)take(256);
    int*   offs   = (int*)take(256);
    int*   te     = (int*)take((size_t)T_TOK * 2 * 4);
    int*   tp     = (int*)take((size_t)T_TOK * 2 * 4);
    unsigned short* pool = (unsigned short*)take((size_t)18 * NCH * DDIM * 2);
    unsigned short* H    = (unsigned short*)take((size_t)ROWS_TOT * IDIM * 2);
    unsigned short* Y    = (unsigned short*)take((size_t)ROWS_TOT * DDIM * 2);

    router_kernel<<<T_TOK / 4, 256, 0, stream>>>(x, gw, seg, gate_out, wdense, sgo, xb);
    bucket_kernel<<<NEXP, 256, 0, stream>>>(wdense, list, wl, cnt, te, tp);
    scan_kernel<<<1, 64, 0, stream>>>(cnt, offs);

    // Gate+up in two N-chunks (weight pool reuse; H columns independent).
    for (int c = 0; c < 2; c++) {
        int c0 = c * NCH;
        wcvt_gu_kernel<<<dim3((NCH / 64) * 16, 18), 256, 0, stream>>>(
            egw, euw, sgp, sup, pool, c0);
        gemm_gateup8<<<dim3(NCH / 128, T_TOK / 256, 9), 512, 0, stream>>>(
            xb, pool, H, list, cnt, offs, c0);
    }

    // Down: single pass, K = IDIM, combine weights folded into the epilogue.
    wcvt_d_kernel<<<dim3((IDIM / 64) * 16, 9), 256, 0, stream>>>(edw, sdw, pool);
    gemm_down8<<<dim3(DDIM / 256, T_TOK / 256, 9), 512, 0, stream>>>(
        H, pool, Y, wl, sgo, cnt, offs);

    combine_kernel<<<T_TOK / 2, 256, 0, stream>>>(Y, te, tp, offs, out0);
}